// Round 1
// baseline (188.398 us; speedup 1.0000x reference)
//
#include <hip/hip_runtime.h>

// Problem constants (fixed by setup_inputs)
#define B_  4
#define C_  128
#define CQ_ 16
#define N_  4096

typedef short          s16x8 __attribute__((ext_vector_type(8)));
typedef unsigned short u16x4 __attribute__((ext_vector_type(4)));
typedef float          f32x4 __attribute__((ext_vector_type(4)));
typedef unsigned short u16;

__device__ __forceinline__ u16 f2bf(float f) {
    unsigned int u = __builtin_bit_cast(unsigned int, f);
    u += 0x7fffu + ((u >> 16) & 1u);           // round-to-nearest-even
    return (u16)(u >> 16);
}
__device__ __forceinline__ float bf2f(u16 h) {
    unsigned int u = ((unsigned int)h) << 16;
    return __builtin_bit_cast(float, u);
}
__device__ __forceinline__ s16x8 ld8bf(const u16* p) {
    return *reinterpret_cast<const s16x8*>(p);
}

// ---------------------------------------------------------------------------
// Projection q,k: q[b,n,j] = sum_c wq[j,c] x[b,c,n] + bq[j]  (j<16), same for k.
// Output layout: Qb/Kb[(b*N+n)*32 + d], d=0..15 bf16-hi, d=16..31 bf16-lo.
// Block: 256 thr = 64 n-cols x 4 c-chunks of 32; partial-reduce through LDS.
// ---------------------------------------------------------------------------
__global__ __launch_bounds__(256) void proj_qk_kernel(
    const float* __restrict__ x, const float* __restrict__ wq, const float* __restrict__ bq,
    const float* __restrict__ wk, const float* __restrict__ bk,
    u16* __restrict__ Qb, u16* __restrict__ Kb)
{
    __shared__ float wqs[CQ_ * C_];
    __shared__ float wks[CQ_ * C_];
    __shared__ float part[2][4][64][17];   // [q/k][chunk][n][j], +1 pad vs banks
    const int tid = threadIdx.x;
    for (int i = tid; i < CQ_ * C_; i += 256) { wqs[i] = wq[i]; wks[i] = wk[i]; }
    __syncthreads();

    const int b  = blockIdx.y;
    const int nl = tid & 63;
    const int n  = blockIdx.x * 64 + nl;
    const int ch = tid >> 6;
    const float* xp = x + ((size_t)b * C_) * N_ + n;

    float qa[CQ_], ka[CQ_];
#pragma unroll
    for (int j = 0; j < CQ_; ++j) { qa[j] = 0.f; ka[j] = 0.f; }
    const int c0 = ch * 32;
    for (int c = c0; c < c0 + 32; ++c) {
        const float xv = xp[(size_t)c * N_];
#pragma unroll
        for (int j = 0; j < CQ_; ++j) {
            qa[j] = fmaf(wqs[j * C_ + c], xv, qa[j]);
            ka[j] = fmaf(wks[j * C_ + c], xv, ka[j]);
        }
    }
#pragma unroll
    for (int j = 0; j < CQ_; ++j) { part[0][ch][nl][j] = qa[j]; part[1][ch][nl][j] = ka[j]; }
    __syncthreads();

    if (tid < 128) {
        const int which = tid >> 6;        // 0 -> q, 1 -> k
        const int n2 = tid & 63;
        const float* bias = which ? bk : bq;
        alignas(16) u16 row[32];
#pragma unroll
        for (int j = 0; j < CQ_; ++j) {
            float v = part[which][0][n2][j] + part[which][1][n2][j]
                    + part[which][2][n2][j] + part[which][3][n2][j] + bias[j];
            u16 h = f2bf(v);
            row[j]        = h;
            row[CQ_ + j]  = f2bf(v - bf2f(h));   // lo residual
        }
        u16* dst = (which ? Kb : Qb) + ((size_t)(b * N_ + blockIdx.x * 64 + n2)) * 32;
#pragma unroll
        for (int i = 0; i < 4; ++i)
            reinterpret_cast<uint4*>(dst)[i] = reinterpret_cast<const uint4*>(row)[i];
    }
}

// ---------------------------------------------------------------------------
// Projection v: v[b,cv,n] = sum_c wv[cv,c] x[b,c,n] + bv[cv].  Output bf16 (B,C,N).
// Grid z splits cv into 4 chunks of 32.
// ---------------------------------------------------------------------------
__global__ __launch_bounds__(256) void proj_v_kernel(
    const float* __restrict__ x, const float* __restrict__ wv, const float* __restrict__ bv,
    u16* __restrict__ Vb)
{
    __shared__ float wvs[32 * C_];
    __shared__ float part[4][64][33];
    const int tid = threadIdx.x;
    const int cv0 = blockIdx.z * 32;
    for (int i = tid; i < 32 * C_; i += 256) wvs[i] = wv[cv0 * C_ + i];
    __syncthreads();

    const int b  = blockIdx.y;
    const int nl = tid & 63;
    const int ch = tid >> 6;
    const int n  = blockIdx.x * 64 + nl;
    const float* xp = x + ((size_t)b * C_) * N_ + n;

    float acc[32];
#pragma unroll
    for (int j = 0; j < 32; ++j) acc[j] = 0.f;
    const int c0 = ch * 32;
    for (int c = c0; c < c0 + 32; ++c) {
        const float xv = xp[(size_t)c * N_];
#pragma unroll
        for (int j = 0; j < 32; ++j) acc[j] = fmaf(wvs[j * C_ + c], xv, acc[j]);
    }
#pragma unroll
    for (int j = 0; j < 32; ++j) part[ch][nl][j] = acc[j];
    __syncthreads();

    const int jq = tid >> 6;
#pragma unroll
    for (int jj = 0; jj < 8; ++jj) {
        const int j = jq * 8 + jj;
        float v = part[0][nl][j] + part[1][nl][j] + part[2][nl][j] + part[3][nl][j]
                + bv[cv0 + j];
        Vb[((size_t)(b * C_ + cv0 + j)) * N_ + blockIdx.x * 64 + nl] = f2bf(v);
    }
}

// ---------------------------------------------------------------------------
// Fused attention. Block = 64 q-rows, 4 waves in 2x2 (c-half x n-half) split.
// Wave (wc,wn) computes QK^T+softmax for n-col nc=2*wn+wc (16 rows), shares P
// via LDS, accumulates O^T for c in [64*wc,64*wc+64) x n-cols {2wn, 2wn+1}.
//   S^T = K . Q^T   via mfma(A=K-frag, B=Q-frag)   (m rows, n cols)
//   O^T = V^T . P^T via mfma(A=V-frag, B=P-frag)   (c rows, n cols)
// hi/lo-packed K=32 trick: frag d0..15 = hi, d16..31 = lo -> 2 MFMAs give
// QhKh + QlKh + QhKl (fp32-quality energy).  No online max (|energy| << 88).
// ---------------------------------------------------------------------------
__global__ __launch_bounds__(256) void attn_kernel(
    const u16* __restrict__ Qb, const u16* __restrict__ Kb, const u16* __restrict__ Vb,
    const float* __restrict__ x, const float* __restrict__ gamma,
    float* __restrict__ out)
{
    __shared__ __align__(16) u16 P_lds[2][64][72];  // [dbuf][n_local][m_local], pad 72
    __shared__ float l_lds[64];

    const int tid  = threadIdx.x;
    const int lane = tid & 63;
    const int l16  = lane & 15;
    const int g    = lane >> 4;       // 0..3
    const int wave = tid >> 6;        // 0..3
    const int wc   = wave & 1;        // c-half
    const int wn   = wave >> 1;       // n-half
    const int nc   = 2 * wn + wc;     // QK column (16 q-rows) owned by this wave
    const int b    = blockIdx.y;
    const int n0   = blockIdx.x * 64;

    // Q B-fragment for this wave's column: B[k=d][col=n], d = 8g..8g+7 of [hi|lo]
    const int qn = n0 + nc * 16 + l16;
    const s16x8 qf = ld8bf(Qb + ((size_t)(b * N_ + qn)) * 32 + 8 * g);

    const u16* kbase = Kb + ((size_t)b * N_ + l16) * 32;
    const u16* vbase = Vb + ((size_t)(b * C_ + 64 * wc + l16)) * N_ + 8 * g;

    f32x4 acc[4][2];
#pragma unroll
    for (int cg = 0; cg < 4; ++cg) { acc[cg][0] = {}; acc[cg][1] = {}; }
    float lpart = 0.f;

    for (int t = 0; t < N_ / 64; ++t) {
        const int m0  = t * 64;
        const int buf = t & 1;

        // ---- S^T = K . Q^T for column nc (4 row-groups of 16 m's) ----
        f32x4 s[4];
#pragma unroll
        for (int mg = 0; mg < 4; ++mg) {
            const u16* kr = kbase + (size_t)(m0 + 16 * mg) * 32;
            s16x8 kf1 = ld8bf(kr + 8 * (g & 1));            // [Kh | Kh]
            s16x8 kf2 = {};                                  // [Kl | 0 ]
            if (g < 2) kf2 = ld8bf(kr + 16 + 8 * g);
            f32x4 z = {};
            z = __builtin_amdgcn_mfma_f32_16x16x32_bf16(kf1, qf, z, 0, 0, 0);
            z = __builtin_amdgcn_mfma_f32_16x16x32_bf16(kf2, qf, z, 0, 0, 0);
            s[mg] = z;
        }

        // ---- P = exp(S^T) -> bf16 -> LDS; accumulate denominator ----
        const int prow = 16 * nc + l16;
#pragma unroll
        for (int mg = 0; mg < 4; ++mg) {
            const u16 e0 = f2bf(__expf(s[mg][0]));
            const u16 e1 = f2bf(__expf(s[mg][1]));
            const u16 e2 = f2bf(__expf(s[mg][2]));
            const u16 e3 = f2bf(__expf(s[mg][3]));
            lpart += bf2f(e0) + bf2f(e1) + bf2f(e2) + bf2f(e3);
            u16x4 pk = { e0, e1, e2, e3 };
            *reinterpret_cast<u16x4*>(&P_lds[buf][prow][16 * mg + 4 * g]) = pk;
        }
        __syncthreads();   // P[buf] visible; dbuf makes one barrier/iter safe

        // ---- O^T += V^T . P^T ----
#pragma unroll
        for (int ss = 0; ss < 2; ++ss) {
            const s16x8 pf0 = ld8bf(&P_lds[buf][16 * (2 * wn)     + l16][32 * ss + 8 * g]);
            const s16x8 pf1 = ld8bf(&P_lds[buf][16 * (2 * wn + 1) + l16][32 * ss + 8 * g]);
#pragma unroll
            for (int cg = 0; cg < 4; ++cg) {
                const s16x8 vf = ld8bf(vbase + (size_t)(16 * cg) * N_ + m0 + 32 * ss);
                acc[cg][0] = __builtin_amdgcn_mfma_f32_16x16x32_bf16(vf, pf0, acc[cg][0], 0, 0, 0);
                acc[cg][1] = __builtin_amdgcn_mfma_f32_16x16x32_bf16(vf, pf1, acc[cg][1], 0, 0, 0);
            }
        }
    }

    // ---- epilogue: denominator, divide, gamma * O + x ----
    lpart += __shfl_xor(lpart, 16);
    lpart += __shfl_xor(lpart, 32);
    if (g == 0) l_lds[16 * nc + l16] = lpart;
    __syncthreads();
    const float inv0 = 1.f / l_lds[16 * (2 * wn)     + l16];
    const float inv1 = 1.f / l_lds[16 * (2 * wn + 1) + l16];
    const float gm = gamma[0];
#pragma unroll
    for (int nf = 0; nf < 2; ++nf) {
        const float inv = nf ? inv1 : inv0;
        const int n = n0 + 16 * (2 * wn + nf) + l16;
#pragma unroll
        for (int cg = 0; cg < 4; ++cg) {
#pragma unroll
            for (int i = 0; i < 4; ++i) {
                const int c = 64 * wc + 16 * cg + 4 * g + i;
                const size_t idx = ((size_t)(b * C_ + c)) * N_ + n;
                out[idx] = gm * acc[cg][nf][i] * inv + x[idx];
            }
        }
    }
}

// ---------------------------------------------------------------------------
extern "C" void kernel_launch(void* const* d_in, const int* in_sizes, int n_in,
                              void* d_out, int out_size, void* d_ws, size_t ws_size,
                              hipStream_t stream)
{
    const float* x     = (const float*)d_in[0];
    const float* wq    = (const float*)d_in[1];
    const float* bq    = (const float*)d_in[2];
    const float* wk    = (const float*)d_in[3];
    const float* bk    = (const float*)d_in[4];
    const float* wv    = (const float*)d_in[5];
    const float* bv    = (const float*)d_in[6];
    const float* gamma = (const float*)d_in[7];
    float* out = (float*)d_out;

    // workspace layout (6 MB total): Qb 1MB | Kb 1MB | Vb 4MB, all bf16 bits
    u16* Qb = (u16*)d_ws;                         // (B,N,32)  [hi|lo]
    u16* Kb = Qb + (size_t)B_ * N_ * 32;          // (B,N,32)  [hi|lo]
    u16* Vb = Kb + (size_t)B_ * N_ * 32;          // (B,C,N)

    proj_qk_kernel<<<dim3(N_ / 64, B_), 256, 0, stream>>>(x, wq, bq, wk, bk, Qb, Kb);
    proj_v_kernel<<<dim3(N_ / 64, B_, C_ / 32), 256, 0, stream>>>(x, wv, bv, Vb);
    attn_kernel<<<dim3(N_ / 64, B_), 256, 0, stream>>>(Qb, Kb, Vb, x, gamma, out);
}

// Round 2
// 132.129 us; speedup vs baseline: 1.4259x; 1.4259x over previous
//
#include <hip/hip_runtime.h>

// Problem constants (fixed by setup_inputs)
#define B_    4
#define C_    128
#define CQ_   16
#define N_    4096
#define SPLIT 4
#define MPER  (N_ / SPLIT)   // 1024 kv-positions per split block

typedef short          s16x8 __attribute__((ext_vector_type(8)));
typedef unsigned short u16x4 __attribute__((ext_vector_type(4)));
typedef float          f32x4 __attribute__((ext_vector_type(4)));
typedef unsigned short u16;

__device__ __forceinline__ u16 f2bf(float f) {
    unsigned int u = __builtin_bit_cast(unsigned int, f);
    u += 0x7fffu + ((u >> 16) & 1u);           // round-to-nearest-even
    return (u16)(u >> 16);
}
__device__ __forceinline__ float bf2f(u16 h) {
    unsigned int u = ((unsigned int)h) << 16;
    return __builtin_bit_cast(float, u);
}
__device__ __forceinline__ s16x8 ld8bf(const u16* p) {
    return *reinterpret_cast<const s16x8*>(p);
}

// ---------------------------------------------------------------------------
// Fused projections, one launch (z=0: q&k, z=1..4: v chunk of 32 channels).
// q[b,n,j] = sum_c wq[j,c] x[b,c,n] + bq[j]; Qb/Kb layout (b,n,32) [hi|lo].
// v[b,cv,n] -> Vb bf16 (b,C,n).
// Block: 256 thr = 64 n-cols x 4 c-chunks of 32; partial-reduce through LDS.
// ---------------------------------------------------------------------------
__global__ __launch_bounds__(256) void proj_all_kernel(
    const float* __restrict__ x,
    const float* __restrict__ wq, const float* __restrict__ bq,
    const float* __restrict__ wk, const float* __restrict__ bk,
    const float* __restrict__ wv, const float* __restrict__ bv,
    u16* __restrict__ Qb, u16* __restrict__ Kb, u16* __restrict__ Vb)
{
    __shared__ float smem[12800];   // 51.2 KB, carved per-branch
    const int tid = threadIdx.x;
    const int b   = blockIdx.y;
    const int nl  = tid & 63;
    const int n   = blockIdx.x * 64 + nl;
    const int ch  = tid >> 6;
    const float* xp = x + ((size_t)b * C_) * N_ + n;

    if (blockIdx.z == 0) {
        // ---------------- q & k projection ----------------
        float* wqs = smem;               // 2048
        float* wks = smem + 2048;        // 2048
        float (*part)[4][64][17] = (float (*)[4][64][17])(smem + 4096);
        for (int i = tid; i < CQ_ * C_; i += 256) { wqs[i] = wq[i]; wks[i] = wk[i]; }
        __syncthreads();

        float qa[CQ_], ka[CQ_];
#pragma unroll
        for (int j = 0; j < CQ_; ++j) { qa[j] = 0.f; ka[j] = 0.f; }
        const int c0 = ch * 32;
        for (int c = c0; c < c0 + 32; ++c) {
            const float xv = xp[(size_t)c * N_];
#pragma unroll
            for (int j = 0; j < CQ_; ++j) {
                qa[j] = fmaf(wqs[j * C_ + c], xv, qa[j]);
                ka[j] = fmaf(wks[j * C_ + c], xv, ka[j]);
            }
        }
#pragma unroll
        for (int j = 0; j < CQ_; ++j) { part[0][ch][nl][j] = qa[j]; part[1][ch][nl][j] = ka[j]; }
        __syncthreads();

        if (tid < 128) {
            const int which = tid >> 6;        // 0 -> q, 1 -> k
            const int n2 = tid & 63;
            const float* bias = which ? bk : bq;
            alignas(16) u16 row[32];
#pragma unroll
            for (int j = 0; j < CQ_; ++j) {
                float v = part[which][0][n2][j] + part[which][1][n2][j]
                        + part[which][2][n2][j] + part[which][3][n2][j] + bias[j];
                u16 h = f2bf(v);
                row[j]       = h;
                row[CQ_ + j] = f2bf(v - bf2f(h));   // lo residual
            }
            u16* dst = (which ? Kb : Qb) + ((size_t)(b * N_ + blockIdx.x * 64 + n2)) * 32;
#pragma unroll
            for (int i = 0; i < 4; ++i)
                reinterpret_cast<uint4*>(dst)[i] = reinterpret_cast<const uint4*>(row)[i];
        }
    } else {
        // ---------------- v projection (32 channels) ----------------
        const int cv0 = (blockIdx.z - 1) * 32;
        float* wvs = smem;               // 4096
        float (*part)[64][33] = (float (*)[64][33])(smem + 4096);
        for (int i = tid; i < 32 * C_; i += 256) wvs[i] = wv[cv0 * C_ + i];
        __syncthreads();

        float acc[32];
#pragma unroll
        for (int j = 0; j < 32; ++j) acc[j] = 0.f;
        const int c0 = ch * 32;
        for (int c = c0; c < c0 + 32; ++c) {
            const float xv = xp[(size_t)c * N_];
#pragma unroll
            for (int j = 0; j < 32; ++j) acc[j] = fmaf(wvs[j * C_ + c], xv, acc[j]);
        }
#pragma unroll
        for (int j = 0; j < 32; ++j) part[ch][nl][j] = acc[j];
        __syncthreads();

        const int jq = tid >> 6;
#pragma unroll
        for (int jj = 0; jj < 8; ++jj) {
            const int j = jq * 8 + jj;
            float v = part[0][nl][j] + part[1][nl][j] + part[2][nl][j] + part[3][nl][j]
                    + bv[cv0 + j];
            Vb[((size_t)(b * C_ + cv0 + j)) * N_ + blockIdx.x * 64 + nl] = f2bf(v);
        }
    }
}

// ---------------------------------------------------------------------------
// Split-KV fused attention (flash-decode style; no online max needed since
// |energy| << 88). Block = 64 q-rows x 1024 kv-positions (blockIdx.z picks
// the kv split). 4 waves in 2x2 (c-half x n-half) split, same as round 0.
// Stores UNNORMALIZED partial O^T (bf16) and partial denominator l (fp32);
// a reduce kernel combines splits and applies gamma*O/l + x.
// ---------------------------------------------------------------------------
__global__ __launch_bounds__(256) void attn_split_kernel(
    const u16* __restrict__ Qb, const u16* __restrict__ Kb, const u16* __restrict__ Vb,
    u16* __restrict__ Opart, float* __restrict__ Lpart)
{
    __shared__ __align__(16) u16 P_lds[2][64][72];  // [dbuf][n_local][m_local], pad 72

    const int tid  = threadIdx.x;
    const int lane = tid & 63;
    const int l16  = lane & 15;
    const int g    = lane >> 4;       // 0..3
    const int wave = tid >> 6;        // 0..3
    const int wc   = wave & 1;        // c-half
    const int wn   = wave >> 1;       // n-half
    const int nc   = 2 * wn + wc;     // QK column (16 q-rows) owned by this wave
    const int b    = blockIdx.y;
    const int n0   = blockIdx.x * 64;
    const int s    = blockIdx.z;
    const int ms   = s * MPER;

    // Q B-fragment for this wave's column: B[k=d][col=n], d = 8g..8g+7 of [hi|lo]
    const int qn = n0 + nc * 16 + l16;
    const s16x8 qf = ld8bf(Qb + ((size_t)(b * N_ + qn)) * 32 + 8 * g);

    const u16* kbase = Kb + ((size_t)b * N_ + l16) * 32;
    const u16* vbase = Vb + ((size_t)(b * C_ + 64 * wc + l16)) * N_ + 8 * g;

    f32x4 acc[4][2];
#pragma unroll
    for (int cg = 0; cg < 4; ++cg) { acc[cg][0] = {}; acc[cg][1] = {}; }
    float lpart = 0.f;

    for (int t = 0; t < MPER / 64; ++t) {
        const int m0  = ms + t * 64;
        const int buf = t & 1;

        // ---- S^T = K . Q^T for column nc (4 row-groups of 16 m's) ----
        f32x4 sacc[4];
#pragma unroll
        for (int mg = 0; mg < 4; ++mg) {
            const u16* kr = kbase + (size_t)(m0 + 16 * mg) * 32;
            s16x8 kf1 = ld8bf(kr + 8 * (g & 1));            // [Kh | Kh]
            s16x8 kf2 = {};                                  // [Kl | 0 ]
            if (g < 2) kf2 = ld8bf(kr + 16 + 8 * g);
            f32x4 z = {};
            z = __builtin_amdgcn_mfma_f32_16x16x32_bf16(kf1, qf, z, 0, 0, 0);
            z = __builtin_amdgcn_mfma_f32_16x16x32_bf16(kf2, qf, z, 0, 0, 0);
            sacc[mg] = z;
        }

        // ---- P = exp(S^T) -> bf16 -> LDS; accumulate denominator ----
        const int prow = 16 * nc + l16;
#pragma unroll
        for (int mg = 0; mg < 4; ++mg) {
            const u16 e0 = f2bf(__expf(sacc[mg][0]));
            const u16 e1 = f2bf(__expf(sacc[mg][1]));
            const u16 e2 = f2bf(__expf(sacc[mg][2]));
            const u16 e3 = f2bf(__expf(sacc[mg][3]));
            lpart += bf2f(e0) + bf2f(e1) + bf2f(e2) + bf2f(e3);
            u16x4 pk = { e0, e1, e2, e3 };
            *reinterpret_cast<u16x4*>(&P_lds[buf][prow][16 * mg + 4 * g]) = pk;
        }
        __syncthreads();   // P[buf] visible; dbuf makes one barrier/iter safe

        // ---- O^T += V^T . P^T ----
#pragma unroll
        for (int ss = 0; ss < 2; ++ss) {
            const s16x8 pf0 = ld8bf(&P_lds[buf][16 * (2 * wn)     + l16][32 * ss + 8 * g]);
            const s16x8 pf1 = ld8bf(&P_lds[buf][16 * (2 * wn + 1) + l16][32 * ss + 8 * g]);
#pragma unroll
            for (int cg = 0; cg < 4; ++cg) {
                const s16x8 vf = ld8bf(vbase + (size_t)(16 * cg) * N_ + m0 + 32 * ss);
                acc[cg][0] = __builtin_amdgcn_mfma_f32_16x16x32_bf16(vf, pf0, acc[cg][0], 0, 0, 0);
                acc[cg][1] = __builtin_amdgcn_mfma_f32_16x16x32_bf16(vf, pf1, acc[cg][1], 0, 0, 0);
            }
        }
    }

    // ---- epilogue: store partial l and unnormalized partial O (bf16) ----
    lpart += __shfl_xor(lpart, 16);
    lpart += __shfl_xor(lpart, 32);
    const size_t sb = (size_t)(s * B_ + b);
    if (g == 0) Lpart[sb * N_ + n0 + 16 * nc + l16] = lpart;

#pragma unroll
    for (int nf = 0; nf < 2; ++nf) {
        const int n = n0 + 16 * (2 * wn + nf) + l16;
#pragma unroll
        for (int cg = 0; cg < 4; ++cg) {
#pragma unroll
            for (int i = 0; i < 4; ++i) {
                const int c = 64 * wc + 16 * cg + 4 * g + i;
                Opart[(sb * C_ + c) * N_ + n] = f2bf(acc[cg][nf][i]);
            }
        }
    }
}

// ---------------------------------------------------------------------------
// Combine splits: out = gamma * (sum_s Opart) / (sum_s Lpart) + x.
// One thread = 4 consecutive n; fully coalesced float4/u16x4 traffic.
// ---------------------------------------------------------------------------
__global__ __launch_bounds__(256) void reduce_kernel(
    const u16* __restrict__ Opart, const float* __restrict__ Lpart,
    const float* __restrict__ x, const float* __restrict__ gamma,
    float* __restrict__ out)
{
    const int t  = blockIdx.x * 256 + threadIdx.x;      // 524288 threads
    const size_t e0 = (size_t)t * 4;                    // < B*C*N = 2^21
    const int n = (int)(e0 & (N_ - 1));
    const int c = (int)((e0 >> 12) & (C_ - 1));
    const int b = (int)(e0 >> 19);

    float o0 = 0.f, o1 = 0.f, o2 = 0.f, o3 = 0.f;
    f32x4 l = {};
#pragma unroll
    for (int s = 0; s < SPLIT; ++s) {
        const size_t sb = (size_t)(s * B_ + b);
        const u16x4 ov = *reinterpret_cast<const u16x4*>(Opart + (sb * C_ + c) * N_ + n);
        const f32x4 lv = *reinterpret_cast<const f32x4*>(Lpart + sb * N_ + n);
        o0 += bf2f(ov[0]); o1 += bf2f(ov[1]); o2 += bf2f(ov[2]); o3 += bf2f(ov[3]);
        l += lv;
    }
    const float gm = gamma[0];
    const f32x4 xv = *reinterpret_cast<const f32x4*>(x + e0);
    f32x4 r;
    r[0] = gm * o0 / l[0] + xv[0];
    r[1] = gm * o1 / l[1] + xv[1];
    r[2] = gm * o2 / l[2] + xv[2];
    r[3] = gm * o3 / l[3] + xv[3];
    *reinterpret_cast<f32x4*>(out + e0) = r;
}

// ---------------------------------------------------------------------------
extern "C" void kernel_launch(void* const* d_in, const int* in_sizes, int n_in,
                              void* d_out, int out_size, void* d_ws, size_t ws_size,
                              hipStream_t stream)
{
    const float* x     = (const float*)d_in[0];
    const float* wq    = (const float*)d_in[1];
    const float* bq    = (const float*)d_in[2];
    const float* wk    = (const float*)d_in[3];
    const float* bk    = (const float*)d_in[4];
    const float* wv    = (const float*)d_in[5];
    const float* bv    = (const float*)d_in[6];
    const float* gamma = (const float*)d_in[7];
    float* out = (float*)d_out;

    // ws layout (~22.5 MB): Qb 1MB | Kb 1MB | Vb 4MB | Opart 16MB | Lpart 256KB
    u16* Qb = (u16*)d_ws;                               // (B,N,32)  [hi|lo]
    u16* Kb = Qb + (size_t)B_ * N_ * 32;                // (B,N,32)  [hi|lo]
    u16* Vb = Kb + (size_t)B_ * N_ * 32;                // (B,C,N)   bf16
    u16* Opart = Vb + (size_t)B_ * C_ * N_;             // (SPLIT,B,C,N) bf16
    float* Lpart = (float*)(Opart + (size_t)SPLIT * B_ * C_ * N_);  // (SPLIT,B,N)

    proj_all_kernel<<<dim3(N_ / 64, B_, 5), 256, 0, stream>>>(
        x, wq, bq, wk, bk, wv, bv, Qb, Kb, Vb);
    attn_split_kernel<<<dim3(N_ / 64, B_, SPLIT), 256, 0, stream>>>(
        Qb, Kb, Vb, Opart, Lpart);
    reduce_kernel<<<(B_ * C_ * N_ / 4) / 256, 256, 0, stream>>>(
        Opart, Lpart, x, gamma, out);
}